// Round 13
// baseline (57.353 us; speedup 1.0000x reference)
//
#include <hip/hip_runtime.h>
#include <hip/hip_bf16.h>

#define VOCAB 100000
#define HALF  256      // HIDDEN/2
#define NC    256      // NUM_CLUSTERS
#define NTOK  16384    // B*S
#define SEGSZ 3200     // ids per segment
#define NSEG  32
#define NHB   16       // histogram/scatter blocks

using frag  = __attribute__((ext_vector_type(8))) short;   // 8 bf16 (A/B operand)
using f32x4 = __attribute__((ext_vector_type(4))) float;   // C/D

static __device__ inline unsigned bfpk(float lo, float hi) {
    union { __hip_bfloat162 h2; unsigned u; } cv;
    cv.h2.x = __float2bfloat16(lo);
    cv.h2.y = __float2bfloat16(hi);
    return cv.u;
}

// async global->LDS, 16B/lane, no VGPR round-trip (size must be literal)
static __device__ inline void gload_lds16(const float* g, float* l) {
    __builtin_amdgcn_global_load_lds(
        (const __attribute__((address_space(1))) void*)g,
        (__attribute__((address_space(3))) void*)l, 16, 0, 0);
}

// ---------------- prep1: 32-seg histograms + coarse transpose ----------------
__global__ __launch_bounds__(1024)
void prep1(const int* __restrict__ ids, const float* __restrict__ coarse_w,
           int* __restrict__ partial, ushort* __restrict__ cT)
{
    __shared__ float tile[64][65];
    __shared__ int lh[NSEG];
    const int tid = threadIdx.x;
    const int b   = blockIdx.x;

    if (b < NHB) {
        if (tid < NSEG) lh[tid] = 0;
        __syncthreads();
        atomicAdd(&lh[ids[b * 1024 + tid] / SEGSZ], 1);
        __syncthreads();
        if (tid < NSEG) partial[b * NSEG + tid] = lh[tid];
    } else {
        const int bt = b - NHB;
        const int ci = (bt >> 2) * 64, hi = (bt & 3) * 64;
#pragma unroll
        for (int p = 0; p < 4; ++p) {
            const int idx = tid + p * 1024;
            const int cl = idx >> 6, hl = idx & 63;
            tile[cl][hl] = coarse_w[(size_t)(ci + cl) * HALF + hi + hl];
        }
        __syncthreads();
#pragma unroll
        for (int p = 0; p < 4; ++p) {
            const int idx = tid + p * 1024;
            const int hl = idx >> 6, cl = idx & 63;
            __hip_bfloat16 v = __float2bfloat16(tile[cl][hl]);
            cT[(size_t)(hi + hl) * NC + ci + cl] = *reinterpret_cast<ushort*>(&v);
        }
    }
}

// ---------------- prep2: 32-wide offsets + rank scatter ----------------
__global__ __launch_bounds__(1024)
void prep2(const int* __restrict__ ids, const int* __restrict__ partial,
           int* __restrict__ seg_off, int* __restrict__ stok, int* __restrict__ sidv)
{
    __shared__ int part_l[NHB][NSEG];
    __shared__ int segoff[NSEG + 1];
    __shared__ int basebs[NSEG];
    __shared__ int cnt[NSEG];
    const int tid = threadIdx.x;
    const int b   = blockIdx.x;

    if (tid < NHB * NSEG) part_l[tid >> 5][tid & 31] = partial[tid];
    __syncthreads();

    if (tid < NSEG) {
        int tot_before = 0, tot_s = 0, base = 0;
        for (int bb = 0; bb < NHB; ++bb) {
            const int v = part_l[bb][tid];
            tot_s += v;
            if (bb < b) base += v;
        }
        for (int s = 0; s < NSEG; ++s)
            if (s < tid)
                for (int bb = 0; bb < NHB; ++bb) tot_before += part_l[bb][s];
        segoff[tid] = tot_before;
        basebs[tid] = base;
        cnt[tid]    = 0;
        if (tid == NSEG - 1) segoff[NSEG] = tot_before + tot_s;
    }
    __syncthreads();

    const int t  = b * 1024 + tid;
    const int id = ids[t];
    const int sg = id / SEGSZ;
    const int r  = atomicAdd(&cnt[sg], 1);
    const int pos = segoff[sg] + basebs[sg] + r;
    stok[pos] = t;
    sidv[pos] = id;

    if (b == 0 && tid <= NSEG) seg_off[tid] = segoff[tid];
}

// ---------------- Kernel A v4b: 4-unit pipelined gather, counted vmcnt ----------------
// block = (row r, eighth e): units k=0..3 = segments 4e+k. Double-buffered LDS;
// unit k+1's async loads issued BEFORE unit k's lookup; counted vmcnt (never 0
// in steady state). FIX vs v4: the tail path's plain-load ds_write is tracked by
// lgkmcnt -- the last block must drain lgkmcnt(0) too before s_barrier.
__global__ __launch_bounds__(256)
void gather_rows(const float* __restrict__ cluster_w,
                 const float* __restrict__ cluster_b,
                 const int*   __restrict__ sidv,
                 const int*   __restrict__ seg_off,
                 __hip_bfloat16* __restrict__ logT)      // [NC][NTOK]
{
    __shared__ float seg[2][3328];     // 2 x 13KB
    const int bid  = blockIdx.x;       // 0..2047
    const int r    = bid >> 3;
    const int e    = bid & 7;
    const int tid  = threadIdx.x;
    const int wave = tid >> 6;
    const int lane = tid & 63;
    const int s0   = e * 4;
    const bool last = (bid == 2047);   // contains segment 31 of row 255

    const float* rowp = cluster_w + (size_t)r * VOCAB;
    const float bias = cluster_b[r];

    int off_[5];
#pragma unroll
    for (int k = 0; k <= 4; ++k) off_[k] = seg_off[s0 + k];

    // issue unit k into buffer buf. tail = the one unit that would overshoot
    // the table end (r=255, s=31): 800 valid floats -> 3 async chunks + plain.
    auto issue = [&](int k, int buf, bool tail) {
        const float* p = rowp + (size_t)(s0 + k) * SEGSZ;
        float* l = seg[buf];
        if (!tail) {
            gload_lds16(p + (wave)     * 256 + lane * 4, l + (wave)     * 256);
            gload_lds16(p + (wave + 4) * 256 + lane * 4, l + (wave + 4) * 256);
            gload_lds16(p + (wave + 8) * 256 + lane * 4, l + (wave + 8) * 256);
            if (wave == 0)
                gload_lds16(p + 12 * 256 + lane * 4, l + 12 * 256);
        } else {
            if (wave < 3)
                gload_lds16(p + wave * 256 + lane * 4, l + wave * 256);
            if (tid < 32) l[768 + tid] = p[768 + tid];   // ds_write -> lgkmcnt!
        }
    };

    issue(0, 0, false);   // unit 0 is never the tail (tail is k=3 of bid 2047)

    for (int k = 0; k < 4; ++k) {
        if (k < 3) issue(k + 1, (k + 1) & 1, last && (k + 1) == 3);

        if (last || k == 3) {
            asm volatile("s_waitcnt vmcnt(0) lgkmcnt(0)" ::: "memory");  // full drain
        } else if (wave == 0) {
            asm volatile("s_waitcnt vmcnt(4)" ::: "memory");
        } else {
            asm volatile("s_waitcnt vmcnt(3)" ::: "memory");
        }
        __builtin_amdgcn_sched_barrier(0);
        __builtin_amdgcn_s_barrier();           // all waves' unit-k data in LDS

        const int sbase = (s0 + k) * SEGSZ;
        const float* l = seg[k & 1];
        for (int i = off_[k] + tid; i < off_[k + 1]; i += 256)
            logT[(size_t)r * NTOK + i] = __float2bfloat16(l[sidv[i] - sbase] + bias);

        __builtin_amdgcn_s_barrier();           // buffer free for next issue
    }
}

// ---------------- Kernel B: softmax + fine + MFMA mixture (unchanged) ----------------
__global__ __launch_bounds__(512)
void mix_mfma(const ushort* __restrict__ logT,     // [NC][NTOK] bf16 bits
              const float*  __restrict__ fine_w,
              const ushort* __restrict__ cT,       // [HALF][NC] bf16 bits, L2-hot
              const int*    __restrict__ stok,
              const int*    __restrict__ sidv,
              float*        __restrict__ out)
{
    __shared__ uint4 ldsA[32][33];
    __shared__ float redu[32][17];
    __shared__ int stok_l[32], sid_l[32];

    const int tid  = threadIdx.x;
    const int base = blockIdx.x * 32;

    if (tid < 32) { stok_l[tid] = stok[base + tid]; sid_l[tid] = sidv[base + tid]; }

    const int s = tid & 31;
    const int g = tid >> 5;
    float v[16];
#pragma unroll
    for (int i = 0; i < 16; ++i) {
        const unsigned u = logT[(size_t)(g * 16 + i) * NTOK + base + s];
        v[i] = __uint_as_float(u << 16);
    }
    float m = v[0];
#pragma unroll
    for (int i = 1; i < 16; ++i) m = fmaxf(m, v[i]);
    redu[s][g] = m;
    __syncthreads();
    float M = redu[s][0];
#pragma unroll
    for (int i = 1; i < 16; ++i) M = fmaxf(M, redu[s][i]);
    __syncthreads();
    float sum = 0.f;
#pragma unroll
    for (int i = 0; i < 16; ++i) { v[i] = __expf(v[i] - M); sum += v[i]; }
    redu[s][g] = sum;
    __syncthreads();
    float tot = 0.f;
#pragma unroll
    for (int i = 0; i < 16; ++i) tot += redu[s][i];
    const float inv = 1.f / tot;

    {
        uint4 u0, u1;
        u0.x = bfpk(v[0] * inv,  v[1] * inv);
        u0.y = bfpk(v[2] * inv,  v[3] * inv);
        u0.z = bfpk(v[4] * inv,  v[5] * inv);
        u0.w = bfpk(v[6] * inv,  v[7] * inv);
        u1.x = bfpk(v[8] * inv,  v[9] * inv);
        u1.y = bfpk(v[10] * inv, v[11] * inv);
        u1.z = bfpk(v[12] * inv, v[13] * inv);
        u1.w = bfpk(v[14] * inv, v[15] * inv);
        ldsA[s][2 * g]     = u0;
        ldsA[s][2 * g + 1] = u1;
    }

    {
        const int sl = tid >> 4, l16 = tid & 15;
        const float4* fs = reinterpret_cast<const float4*>(fine_w + (size_t)sid_l[sl] * HALF);
        float4* fd = reinterpret_cast<float4*>(out + (size_t)stok_l[sl] * 512);
#pragma unroll
        for (int p = 0; p < 4; ++p) fd[l16 + 16 * p] = fs[l16 + 16 * p];
    }
    __syncthreads();

    const int w    = tid >> 6;
    const int lane = tid & 63;
    const int arow = (w & 1) * 16 + (lane & 15);
    const int ngrp = (w >> 1) * 4;
    f32x4 acc[4];
#pragma unroll
    for (int q = 0; q < 4; ++q) acc[q] = (f32x4){0.f, 0.f, 0.f, 0.f};

    for (int ch = 0; ch < 8; ++ch) {
        const frag a = *reinterpret_cast<const frag*>(&ldsA[arow][ch * 4 + (lane >> 4)]);
#pragma unroll
        for (int q = 0; q < 4; ++q) {
            const int n = (ngrp + q) * 16 + (lane & 15);
            const frag b = *reinterpret_cast<const frag*>(
                cT + (size_t)n * NC + ch * 32 + (lane >> 4) * 8);
            acc[q] = __builtin_amdgcn_mfma_f32_16x16x32_bf16(a, b, acc[q], 0, 0, 0);
        }
    }

#pragma unroll
    for (int q = 0; q < 4; ++q) {
        const int col = (ngrp + q) * 16 + (lane & 15);
#pragma unroll
        for (int r = 0; r < 4; ++r) {
            const int srow = (w & 1) * 16 + (lane >> 4) * 4 + r;
            out[(size_t)stok_l[srow] * 512 + 256 + col] = acc[q][r];
        }
    }
}

extern "C" void kernel_launch(void* const* d_in, const int* in_sizes, int n_in,
                              void* d_out, int out_size, void* d_ws, size_t ws_size,
                              hipStream_t stream) {
    const int*   ids       = (const int*)  d_in[0];
    const float* fine_w    = (const float*)d_in[1];
    const float* coarse_w  = (const float*)d_in[2];
    const float* cluster_w = (const float*)d_in[3];
    const float* cluster_b = (const float*)d_in[4];
    float*       out       = (float*)d_out;

    int* partial = (int*)d_ws;                    // [NHB*NSEG]
    int* seg_off = partial + NHB * NSEG;          // [NSEG+1] (pad 64)
    int* stok    = seg_off + 64;                  // [NTOK]
    int* sidv    = stok + NTOK;                   // [NTOK]
    __hip_bfloat16* logT = (__hip_bfloat16*)(sidv + NTOK);   // [NC*NTOK]
    ushort* cT = (ushort*)(logT + (size_t)NC * NTOK);        // [HALF*NC]

    const size_t need = (size_t)(NHB * NSEG + 64 + 2 * NTOK) * sizeof(int)
                      + (size_t)NC * NTOK * 2 + (size_t)HALF * NC * 2;
    if (ws_size < need) return;   // not expected

    hipLaunchKernelGGL(prep1, dim3(2 * NHB), dim3(1024), 0, stream,
                       ids, coarse_w, partial, cT);
    hipLaunchKernelGGL(prep2, dim3(NHB), dim3(1024), 0, stream,
                       ids, partial, seg_off, stok, sidv);
    hipLaunchKernelGGL(gather_rows, dim3(NC * 8), dim3(256), 0, stream,
                       cluster_w, cluster_b, sidv, seg_off, logT);
    hipLaunchKernelGGL(mix_mfma, dim3(NTOK / 32), dim3(512), 0, stream,
                       (const ushort*)logT, fine_w, cT, stok, sidv, out);
}

// Round 15
// 57.040 us; speedup vs baseline: 1.0055x; 1.0055x over previous
//
#include <hip/hip_runtime.h>
#include <hip/hip_bf16.h>

#define VOCAB 100000
#define HALF  256      // HIDDEN/2
#define NC    256      // NUM_CLUSTERS
#define NTOK  16384    // B*S
#define SEG2  1024     // floats per gather unit (4 KB)
#define NSEG2 100      // 98 real units (id>>10 <= 97) + 2 pad
#define RUNS  25       // 4 units per wave-run, 100/4
#define NHB   16       // histogram/scatter blocks

using frag  = __attribute__((ext_vector_type(8))) short;   // 8 bf16 (A/B operand)
using f32x4 = __attribute__((ext_vector_type(4))) float;   // C/D

static __device__ inline unsigned bfpk(float lo, float hi) {
    union { __hip_bfloat162 h2; unsigned u; } cv;
    cv.h2.x = __float2bfloat16(lo);
    cv.h2.y = __float2bfloat16(hi);
    return cv.u;
}

// async global->LDS, 16B/lane (size must be literal)
static __device__ inline void gload_lds16(const float* g, float* l) {
    __builtin_amdgcn_global_load_lds(
        (const __attribute__((address_space(1))) void*)g,
        (__attribute__((address_space(3))) void*)l, 16, 0, 0);
}

// ---------------- prep1: 100-bucket histograms + coarse transpose ----------------
__global__ __launch_bounds__(1024)
void prep1(const int* __restrict__ ids, const float* __restrict__ coarse_w,
           int* __restrict__ partial, ushort* __restrict__ cT)
{
    __shared__ float tile[64][65];
    __shared__ int lh[NSEG2];
    const int tid = threadIdx.x;
    const int b   = blockIdx.x;

    if (b < NHB) {
        if (tid < NSEG2) lh[tid] = 0;
        __syncthreads();
        atomicAdd(&lh[ids[b * 1024 + tid] >> 10], 1);
        __syncthreads();
        if (tid < NSEG2) partial[b * NSEG2 + tid] = lh[tid];
    } else {
        const int bt = b - NHB;
        const int ci = (bt >> 2) * 64, hi = (bt & 3) * 64;
#pragma unroll
        for (int p = 0; p < 4; ++p) {
            const int idx = tid + p * 1024;
            const int cl = idx >> 6, hl = idx & 63;
            tile[cl][hl] = coarse_w[(size_t)(ci + cl) * HALF + hi + hl];
        }
        __syncthreads();
#pragma unroll
        for (int p = 0; p < 4; ++p) {
            const int idx = tid + p * 1024;
            const int hl = idx >> 6, cl = idx & 63;
            __hip_bfloat16 v = __float2bfloat16(tile[cl][hl]);
            cT[(size_t)(hi + hl) * NC + ci + cl] = *reinterpret_cast<ushort*>(&v);
        }
    }
}

// ---------------- prep2: 100-wide offsets + rank scatter ----------------
// FIX vs r14: part_l has NHB*NSEG2 = 1600 entries > 1024 threads -- must
// grid-stride the staging load (rows 10..15 were uninitialized -> OOB scatter).
__global__ __launch_bounds__(1024)
void prep2(const int* __restrict__ ids, const int* __restrict__ partial,
           int* __restrict__ seg_off, int* __restrict__ stok, int* __restrict__ sidv)
{
    __shared__ int part_l[NHB][NSEG2];     // 6.4 KB
    __shared__ int colt[NSEG2];
    __shared__ int segoff[NSEG2 + 1];
    __shared__ int basebs[NSEG2];
    __shared__ int cnt[NSEG2];
    const int tid = threadIdx.x;
    const int b   = blockIdx.x;

    for (int e = tid; e < NHB * NSEG2; e += 1024)
        part_l[e / NSEG2][e % NSEG2] = partial[e];
    __syncthreads();

    if (tid < NSEG2) {
        int tot_s = 0, base = 0;
        for (int bb = 0; bb < NHB; ++bb) {
            const int v = part_l[bb][tid];
            tot_s += v;
            if (bb < b) base += v;
        }
        colt[tid]   = tot_s;
        basebs[tid] = base;
        cnt[tid]    = 0;
    }
    __syncthreads();
    if (tid < NSEG2) {
        int tb = 0;
        for (int s = 0; s < tid; ++s) tb += colt[s];
        segoff[tid] = tb;
        if (tid == NSEG2 - 1) segoff[NSEG2] = tb + colt[tid];
    }
    __syncthreads();

    const int t  = b * 1024 + tid;
    const int id = ids[t];
    const int sg = id >> 10;
    const int r  = atomicAdd(&cnt[sg], 1);
    const int pos = segoff[sg] + basebs[sg] + r;
    stok[pos] = t;
    sidv[pos] = id;

    if (b == 0 && tid <= NSEG2) seg_off[tid] = segoff[tid];
}

// ---------------- Kernel A v5: wave-private pipelined gather, NO block barriers ----------
// wave W = bid*4+wv owns row r = W/25, units s = 4*(W%25) .. +3 (4 KB each).
// Per-wave 2x4KB LDS dbuf; wave-local counted vmcnt; tail ids read via global fallback.
__global__ __launch_bounds__(256)
void gather_rows(const float* __restrict__ cluster_w,
                 const float* __restrict__ cluster_b,
                 const int*   __restrict__ sidv,
                 const int*   __restrict__ seg_off,
                 __hip_bfloat16* __restrict__ logT)      // [NC][NTOK]
{
    __shared__ float seg[4][2][SEG2];   // 32 KB: wave-private double buffers
    const int tid  = threadIdx.x;
    const int wv   = tid >> 6;
    const int lane = tid & 63;
    const int W    = blockIdx.x * 4 + wv;   // 0..6399
    const int r    = W / RUNS;              // 0..255
    const int run  = W - r * RUNS;          // 0..24
    const int s0   = run * 4;

    const float* rowp = cluster_w + (size_t)r * VOCAB;
    const float bias = cluster_b[r];

    // chunks (256-float / 1KB granules) staged for unit s: 4 normal, 2 for s=97, 0 for pads
    auto nch = [&](int s) {
        int v = VOCAB - s * SEG2;
        v = v < 0 ? 0 : (v > SEG2 ? SEG2 : v);
        return v >> 8;
    };
    auto issue = [&](int s, int buf) {
        const int c = nch(s);
        const float* p = rowp + s * SEG2;
        float* l = &seg[wv][buf][0];
        for (int k = 0; k < c; ++k)
            gload_lds16(p + k * 256 + lane * 4, l + k * 256);
    };

    int off_[5];
#pragma unroll
    for (int j = 0; j <= 4; ++j) off_[j] = seg_off[s0 + j];

    issue(s0, 0);
    for (int j = 0; j < 4; ++j) {
        const int s = s0 + j;
        int nw = 0;
        if (j < 3) { issue(s + 1, (j + 1) & 1); nw = nch(s + 1); }

        if (nw == 4)      asm volatile("s_waitcnt vmcnt(4)" ::: "memory");
        else if (nw == 2) asm volatile("s_waitcnt vmcnt(2)" ::: "memory");
        else              asm volatile("s_waitcnt vmcnt(0)" ::: "memory");
        __builtin_amdgcn_sched_barrier(0);

        const int sbase  = s * SEG2;
        const int staged = nch(s) << 8;
        const float* l = &seg[wv][j & 1][0];
        for (int i = off_[j] + lane; i < off_[j + 1]; i += 64) {
            const int id  = sidv[i];
            const int idx = id - sbase;
            float val;
            if (idx < staged) val = l[idx];
            else              val = rowp[id];    // seg-97 remainder only (~26 ids/row)
            logT[(size_t)r * NTOK + i] = __float2bfloat16(val + bias);
        }
    }
}

// ---------------- Kernel B: softmax + fine + MFMA mixture (unchanged) ----------------
__global__ __launch_bounds__(512)
void mix_mfma(const ushort* __restrict__ logT,     // [NC][NTOK] bf16 bits
              const float*  __restrict__ fine_w,
              const ushort* __restrict__ cT,       // [HALF][NC] bf16 bits, L2-hot
              const int*    __restrict__ stok,
              const int*    __restrict__ sidv,
              float*        __restrict__ out)
{
    __shared__ uint4 ldsA[32][33];
    __shared__ float redu[32][17];
    __shared__ int stok_l[32], sid_l[32];

    const int tid  = threadIdx.x;
    const int base = blockIdx.x * 32;

    if (tid < 32) { stok_l[tid] = stok[base + tid]; sid_l[tid] = sidv[base + tid]; }

    const int s = tid & 31;
    const int g = tid >> 5;
    float v[16];
#pragma unroll
    for (int i = 0; i < 16; ++i) {
        const unsigned u = logT[(size_t)(g * 16 + i) * NTOK + base + s];
        v[i] = __uint_as_float(u << 16);
    }
    float m = v[0];
#pragma unroll
    for (int i = 1; i < 16; ++i) m = fmaxf(m, v[i]);
    redu[s][g] = m;
    __syncthreads();
    float M = redu[s][0];
#pragma unroll
    for (int i = 1; i < 16; ++i) M = fmaxf(M, redu[s][i]);
    __syncthreads();
    float sum = 0.f;
#pragma unroll
    for (int i = 0; i < 16; ++i) { v[i] = __expf(v[i] - M); sum += v[i]; }
    redu[s][g] = sum;
    __syncthreads();
    float tot = 0.f;
#pragma unroll
    for (int i = 0; i < 16; ++i) tot += redu[s][i];
    const float inv = 1.f / tot;

    {
        uint4 u0, u1;
        u0.x = bfpk(v[0] * inv,  v[1] * inv);
        u0.y = bfpk(v[2] * inv,  v[3] * inv);
        u0.z = bfpk(v[4] * inv,  v[5] * inv);
        u0.w = bfpk(v[6] * inv,  v[7] * inv);
        u1.x = bfpk(v[8] * inv,  v[9] * inv);
        u1.y = bfpk(v[10] * inv, v[11] * inv);
        u1.z = bfpk(v[12] * inv, v[13] * inv);
        u1.w = bfpk(v[14] * inv, v[15] * inv);
        ldsA[s][2 * g]     = u0;
        ldsA[s][2 * g + 1] = u1;
    }

    {
        const int sl = tid >> 4, l16 = tid & 15;
        const float4* fs = reinterpret_cast<const float4*>(fine_w + (size_t)sid_l[sl] * HALF);
        float4* fd = reinterpret_cast<float4*>(out + (size_t)stok_l[sl] * 512);
#pragma unroll
        for (int p = 0; p < 4; ++p) fd[l16 + 16 * p] = fs[l16 + 16 * p];
    }
    __syncthreads();

    const int w    = tid >> 6;
    const int lane = tid & 63;
    const int arow = (w & 1) * 16 + (lane & 15);
    const int ngrp = (w >> 1) * 4;
    f32x4 acc[4];
#pragma unroll
    for (int q = 0; q < 4; ++q) acc[q] = (f32x4){0.f, 0.f, 0.f, 0.f};

    for (int ch = 0; ch < 8; ++ch) {
        const frag a = *reinterpret_cast<const frag*>(&ldsA[arow][ch * 4 + (lane >> 4)]);
#pragma unroll
        for (int q = 0; q < 4; ++q) {
            const int n = (ngrp + q) * 16 + (lane & 15);
            const frag b = *reinterpret_cast<const frag*>(
                cT + (size_t)n * NC + ch * 32 + (lane >> 4) * 8);
            acc[q] = __builtin_amdgcn_mfma_f32_16x16x32_bf16(a, b, acc[q], 0, 0, 0);
        }
    }

#pragma unroll
    for (int q = 0; q < 4; ++q) {
        const int col = (ngrp + q) * 16 + (lane & 15);
#pragma unroll
        for (int r = 0; r < 4; ++r) {
            const int srow = (w & 1) * 16 + (lane >> 4) * 4 + r;
            out[(size_t)stok_l[srow] * 512 + 256 + col] = acc[q][r];
        }
    }
}

extern "C" void kernel_launch(void* const* d_in, const int* in_sizes, int n_in,
                              void* d_out, int out_size, void* d_ws, size_t ws_size,
                              hipStream_t stream) {
    const int*   ids       = (const int*)  d_in[0];
    const float* fine_w    = (const float*)d_in[1];
    const float* coarse_w  = (const float*)d_in[2];
    const float* cluster_w = (const float*)d_in[3];
    const float* cluster_b = (const float*)d_in[4];
    float*       out       = (float*)d_out;

    int* partial = (int*)d_ws;                    // [NHB*NSEG2 = 1600]
    int* seg_off = partial + NHB * NSEG2;         // [NSEG2+1] (pad 128)
    int* stok    = seg_off + 128;                 // [NTOK]
    int* sidv    = stok + NTOK;                   // [NTOK]
    __hip_bfloat16* logT = (__hip_bfloat16*)(sidv + NTOK);   // [NC*NTOK]
    ushort* cT = (ushort*)(logT + (size_t)NC * NTOK);        // [HALF*NC]

    const size_t need = (size_t)(NHB * NSEG2 + 128 + 2 * NTOK) * sizeof(int)
                      + (size_t)NC * NTOK * 2 + (size_t)HALF * NC * 2;
    if (ws_size < need) return;   // not expected

    hipLaunchKernelGGL(prep1, dim3(2 * NHB), dim3(1024), 0, stream,
                       ids, coarse_w, partial, cT);
    hipLaunchKernelGGL(prep2, dim3(NHB), dim3(1024), 0, stream,
                       ids, partial, seg_off, stok, sidv);
    hipLaunchKernelGGL(gather_rows, dim3(NC * RUNS / 4), dim3(256), 0, stream,
                       cluster_w, cluster_b, sidv, seg_off, logT);
    hipLaunchKernelGGL(mix_mfma, dim3(NTOK / 32), dim3(512), 0, stream,
                       (const ushort*)logT, fine_w, cT, stok, sidv, out);
}

// Round 17
// 56.714 us; speedup vs baseline: 1.0113x; 1.0058x over previous
//
#include <hip/hip_runtime.h>
#include <hip/hip_bf16.h>

#define VOCAB 100000
#define HALF  256      // HIDDEN/2
#define NC    256      // NUM_CLUSTERS
#define NTOK  16384    // B*S
#define SEG2  1024     // floats per gather unit (4 KB)
#define NSEG2 100      // 98 real units (id>>10 <= 97) + 2 pad
#define RUNS  25       // 4 units per wave-run
#define NHB   16       // histogram/scatter blocks

using frag  = __attribute__((ext_vector_type(8))) short;   // 8 bf16 (A/B operand)
using f32x4 = __attribute__((ext_vector_type(4))) float;   // C/D

static __device__ inline unsigned bfpk(float lo, float hi) {
    union { __hip_bfloat162 h2; unsigned u; } cv;
    cv.h2.x = __float2bfloat16(lo);
    cv.h2.y = __float2bfloat16(hi);
    return cv.u;
}

// async global->LDS, 16B/lane (size must be literal)
static __device__ inline void gload_lds16(const float* g, float* l) {
    __builtin_amdgcn_global_load_lds(
        (const __attribute__((address_space(1))) void*)g,
        (__attribute__((address_space(3))) void*)l, 16, 0, 0);
}

// ---------------- prep1: 100-bucket histograms + coarse transpose ----------------
__global__ __launch_bounds__(1024)
void prep1(const int* __restrict__ ids, const float* __restrict__ coarse_w,
           int* __restrict__ partial, ushort* __restrict__ cT)
{
    __shared__ float tile[64][65];
    __shared__ int lh[NSEG2];
    const int tid = threadIdx.x;
    const int b   = blockIdx.x;

    if (b < NHB) {
        if (tid < NSEG2) lh[tid] = 0;
        __syncthreads();
        atomicAdd(&lh[ids[b * 1024 + tid] >> 10], 1);
        __syncthreads();
        if (tid < NSEG2) partial[b * NSEG2 + tid] = lh[tid];
    } else {
        const int bt = b - NHB;
        const int ci = (bt >> 2) * 64, hi = (bt & 3) * 64;
#pragma unroll
        for (int p = 0; p < 4; ++p) {
            const int idx = tid + p * 1024;
            const int cl = idx >> 6, hl = idx & 63;
            tile[cl][hl] = coarse_w[(size_t)(ci + cl) * HALF + hi + hl];
        }
        __syncthreads();
#pragma unroll
        for (int p = 0; p < 4; ++p) {
            const int idx = tid + p * 1024;
            const int hl = idx >> 6, cl = idx & 63;
            __hip_bfloat16 v = __float2bfloat16(tile[cl][hl]);
            cT[(size_t)(hi + hl) * NC + ci + cl] = *reinterpret_cast<ushort*>(&v);
        }
    }
}

// ---------------- prep2: 100-wide offsets + rank scatter ----------------
__global__ __launch_bounds__(1024)
void prep2(const int* __restrict__ ids, const int* __restrict__ partial,
           int* __restrict__ seg_off, int* __restrict__ stok, int* __restrict__ sidv)
{
    __shared__ int part_l[NHB][NSEG2];
    __shared__ int colt[NSEG2];
    __shared__ int segoff[NSEG2 + 1];
    __shared__ int basebs[NSEG2];
    __shared__ int cnt[NSEG2];
    const int tid = threadIdx.x;
    const int b   = blockIdx.x;

    for (int e = tid; e < NHB * NSEG2; e += 1024)
        part_l[e / NSEG2][e % NSEG2] = partial[e];
    __syncthreads();

    if (tid < NSEG2) {
        int tot_s = 0, base = 0;
        for (int bb = 0; bb < NHB; ++bb) {
            const int v = part_l[bb][tid];
            tot_s += v;
            if (bb < b) base += v;
        }
        colt[tid]   = tot_s;
        basebs[tid] = base;
        cnt[tid]    = 0;
    }
    __syncthreads();
    if (tid < NSEG2) {
        int tb = 0;
        for (int s = 0; s < tid; ++s) tb += colt[s];
        segoff[tid] = tb;
        if (tid == NSEG2 - 1) segoff[NSEG2] = tb + colt[tid];
    }
    __syncthreads();

    const int t  = b * 1024 + tid;
    const int id = ids[t];
    const int sg = id >> 10;
    const int r  = atomicAdd(&cnt[sg], 1);
    const int pos = segoff[sg] + basebs[sg] + r;
    stok[pos] = t;
    sidv[pos] = id;

    if (b == 0 && tid <= NSEG2) seg_off[tid] = segoff[tid];
}

// ---------------- Kernel A v6b: pure-stream FIFO gather ----------------
// FIX vs r16: staged_ must count only FULLY-STAGED 256-float chunks
// ((v>>8)<<8): segment 97 stages 512 floats, not 672 -- ids in the
// unstaged band [512,672) take the global fallback.
__global__ __launch_bounds__(256)
void gather_rows(const float* __restrict__ cluster_w,
                 const float* __restrict__ cluster_b,
                 const int*   __restrict__ sidv,
                 const int*   __restrict__ seg_off,
                 __hip_bfloat16* __restrict__ logT)      // [NC][NTOK]
{
    __shared__ float seg[4][2][SEG2];   // 32 KB: wave-private double buffers
    const int tid  = threadIdx.x;
    const int wv   = tid >> 6;
    const int lane = tid & 63;
    const int W    = blockIdx.x * 4 + wv;   // 0..6399
    const int r    = W / RUNS;              // 0..255
    const int run  = W - r * RUNS;          // 0..24
    const int s0   = run * 4;

    const float* rowp = cluster_w + (size_t)r * VOCAB;
    const float bias = cluster_b[r];

    int off_[5];
#pragma unroll
    for (int j = 0; j <= 4; ++j) off_[j] = seg_off[s0 + j];

    // ---- eager sidv prefetch: 4 units x 4 predicated dwords -> regs ----
    int nid[4][4];
#pragma unroll
    for (int j = 0; j < 4; ++j)
#pragma unroll
        for (int q = 0; q < 4; ++q) {
            int i = off_[j] + q * 64 + lane;
            i = (i < off_[j + 1]) ? i : (NTOK - 1);   // clamp (value unused when OOB)
            nid[j][q] = sidv[i];
        }

    // fully-staged floats per unit: whole 256-float chunks only
    int staged_[4];
#pragma unroll
    for (int j = 0; j < 4; ++j) {
        int v = VOCAB - (s0 + j) * SEG2;
        v = v < 0 ? 0 : (v > SEG2 ? SEG2 : v);
        staged_[j] = (v >> 8) << 8;      // 1024 normal; 512 for s=97; 0 for pads
    }

    // issue exactly 4 gather chunks per unit (clamped source for short units)
    auto issue = [&](int j, int buf) {
        const int sb = (s0 + j) * SEG2;
#pragma unroll
        for (int k = 0; k < 4; ++k) {
            int o = sb + k * 256;
            o = (o + 256 <= VOCAB) ? o : 0;          // clamp: in-bounds dummy
            gload_lds16(rowp + o + lane * 4, &seg[wv][buf][k * 256]);
        }
    };

    issue(0, 0);
#pragma unroll
    for (int j = 0; j < 4; ++j) {
        if (j < 3) issue(j + 1, (j + 1) & 1);

        if (j < 3) asm volatile("s_waitcnt vmcnt(4)" ::: "memory");
        else       asm volatile("s_waitcnt vmcnt(0)" ::: "memory");
        __builtin_amdgcn_sched_barrier(0);

        const int sbase  = (s0 + j) * SEG2;
        const int staged = staged_[j];
        const int cnt    = off_[j + 1] - off_[j];
        const float* l = &seg[wv][j & 1][0];

#pragma unroll
        for (int q = 0; q < 4; ++q) {
            if (q * 64 + lane < cnt) {
                const int id  = nid[j][q];
                const int idx = id - sbase;
                float val;
                if (idx >= 0 && idx < staged) val = l[idx];
                else                          val = rowp[id];   // unstaged band only
                logT[(size_t)r * NTOK + off_[j] + q * 64 + lane] =
                    __float2bfloat16(val + bias);
            }
        }
        // remainder (cnt > 256: statistically never, correctness always)
        for (int i = off_[j] + 256 + lane; i < off_[j + 1]; i += 64) {
            const int id  = sidv[i];
            const int idx = id - sbase;
            float val;
            if (idx >= 0 && idx < staged) val = l[idx];
            else                          val = rowp[id];
            logT[(size_t)r * NTOK + i] = __float2bfloat16(val + bias);
        }
    }
}

// ---------------- Kernel B: softmax + fine + MFMA mixture (unchanged) ----------------
__global__ __launch_bounds__(512)
void mix_mfma(const ushort* __restrict__ logT,     // [NC][NTOK] bf16 bits
              const float*  __restrict__ fine_w,
              const ushort* __restrict__ cT,       // [HALF][NC] bf16 bits, L2-hot
              const int*    __restrict__ stok,
              const int*    __restrict__ sidv,
              float*        __restrict__ out)
{
    __shared__ uint4 ldsA[32][33];
    __shared__ float redu[32][17];
    __shared__ int stok_l[32], sid_l[32];

    const int tid  = threadIdx.x;
    const int base = blockIdx.x * 32;

    if (tid < 32) { stok_l[tid] = stok[base + tid]; sid_l[tid] = sidv[base + tid]; }

    const int s = tid & 31;
    const int g = tid >> 5;
    float v[16];
#pragma unroll
    for (int i = 0; i < 16; ++i) {
        const unsigned u = logT[(size_t)(g * 16 + i) * NTOK + base + s];
        v[i] = __uint_as_float(u << 16);
    }
    float m = v[0];
#pragma unroll
    for (int i = 1; i < 16; ++i) m = fmaxf(m, v[i]);
    redu[s][g] = m;
    __syncthreads();
    float M = redu[s][0];
#pragma unroll
    for (int i = 1; i < 16; ++i) M = fmaxf(M, redu[s][i]);
    __syncthreads();
    float sum = 0.f;
#pragma unroll
    for (int i = 0; i < 16; ++i) { v[i] = __expf(v[i] - M); sum += v[i]; }
    redu[s][g] = sum;
    __syncthreads();
    float tot = 0.f;
#pragma unroll
    for (int i = 0; i < 16; ++i) tot += redu[s][i];
    const float inv = 1.f / tot;

    {
        uint4 u0, u1;
        u0.x = bfpk(v[0] * inv,  v[1] * inv);
        u0.y = bfpk(v[2] * inv,  v[3] * inv);
        u0.z = bfpk(v[4] * inv,  v[5] * inv);
        u0.w = bfpk(v[6] * inv,  v[7] * inv);
        u1.x = bfpk(v[8] * inv,  v[9] * inv);
        u1.y = bfpk(v[10] * inv, v[11] * inv);
        u1.z = bfpk(v[12] * inv, v[13] * inv);
        u1.w = bfpk(v[14] * inv, v[15] * inv);
        ldsA[s][2 * g]     = u0;
        ldsA[s][2 * g + 1] = u1;
    }

    {
        const int sl = tid >> 4, l16 = tid & 15;
        const float4* fs = reinterpret_cast<const float4*>(fine_w + (size_t)sid_l[sl] * HALF);
        float4* fd = reinterpret_cast<float4*>(out + (size_t)stok_l[sl] * 512);
#pragma unroll
        for (int p = 0; p < 4; ++p) fd[l16 + 16 * p] = fs[l16 + 16 * p];
    }
    __syncthreads();

    const int w    = tid >> 6;
    const int lane = tid & 63;
    const int arow = (w & 1) * 16 + (lane & 15);
    const int ngrp = (w >> 1) * 4;
    f32x4 acc[4];
#pragma unroll
    for (int q = 0; q < 4; ++q) acc[q] = (f32x4){0.f, 0.f, 0.f, 0.f};

    for (int ch = 0; ch < 8; ++ch) {
        const frag a = *reinterpret_cast<const frag*>(&ldsA[arow][ch * 4 + (lane >> 4)]);
#pragma unroll
        for (int q = 0; q < 4; ++q) {
            const int n = (ngrp + q) * 16 + (lane & 15);
            const frag b = *reinterpret_cast<const frag*>(
                cT + (size_t)n * NC + ch * 32 + (lane >> 4) * 8);
            acc[q] = __builtin_amdgcn_mfma_f32_16x16x32_bf16(a, b, acc[q], 0, 0, 0);
        }
    }

#pragma unroll
    for (int q = 0; q < 4; ++q) {
        const int col = (ngrp + q) * 16 + (lane & 15);
#pragma unroll
        for (int r = 0; r < 4; ++r) {
            const int srow = (w & 1) * 16 + (lane >> 4) * 4 + r;
            out[(size_t)stok_l[srow] * 512 + 256 + col] = acc[q][r];
        }
    }
}

extern "C" void kernel_launch(void* const* d_in, const int* in_sizes, int n_in,
                              void* d_out, int out_size, void* d_ws, size_t ws_size,
                              hipStream_t stream) {
    const int*   ids       = (const int*)  d_in[0];
    const float* fine_w    = (const float*)d_in[1];
    const float* coarse_w  = (const float*)d_in[2];
    const float* cluster_w = (const float*)d_in[3];
    const float* cluster_b = (const float*)d_in[4];
    float*       out       = (float*)d_out;

    int* partial = (int*)d_ws;                    // [NHB*NSEG2 = 1600]
    int* seg_off = partial + NHB * NSEG2;         // [NSEG2+1] (pad 128)
    int* stok    = seg_off + 128;                 // [NTOK]
    int* sidv    = stok + NTOK;                   // [NTOK]
    __hip_bfloat16* logT = (__hip_bfloat16*)(sidv + NTOK);   // [NC*NTOK]
    ushort* cT = (ushort*)(logT + (size_t)NC * NTOK);        // [HALF*NC]

    const size_t need = (size_t)(NHB * NSEG2 + 128 + 2 * NTOK) * sizeof(int)
                      + (size_t)NC * NTOK * 2 + (size_t)HALF * NC * 2;
    if (ws_size < need) return;   // not expected

    hipLaunchKernelGGL(prep1, dim3(2 * NHB), dim3(1024), 0, stream,
                       ids, coarse_w, partial, cT);
    hipLaunchKernelGGL(prep2, dim3(NHB), dim3(1024), 0, stream,
                       ids, partial, seg_off, stok, sidv);
    hipLaunchKernelGGL(gather_rows, dim3(NC * RUNS / 4), dim3(256), 0, stream,
                       cluster_w, cluster_b, sidv, seg_off, logT);
    hipLaunchKernelGGL(mix_mfma, dim3(NTOK / 32), dim3(512), 0, stream,
                       (const ushort*)logT, fine_w, cT, stok, sidv, out);
}